// Round 8
// baseline (186.136 us; speedup 1.0000x reference)
//
#include <hip/hip_runtime.h>
#include <hip/hip_bf16.h>

typedef short s16x8 __attribute__((ext_vector_type(8)));
typedef short s16x4 __attribute__((ext_vector_type(4)));
typedef float f32x4 __attribute__((ext_vector_type(4)));

#define TB 4            // batch elements per group (R8: halved; 128-thread blocks)
#define NBG 16          // groups per block; grid 1024 = exactly 4 blocks/CU
#define NTHREADS 128    // 2 waves/block
#define HALO 46         // gtile positions per batch (pos -2 .. 43)
#define GSTRIDE 2216    // shorts per batch in gtile (8*odd: bank-decorrelated)
#define USTRIDE 50      // floats per batch in u_s halo
#define NT 3            // stage-2 N tiles (48 cols, >=37 zero-padded; k=240 = b2 row)
#define GT_SHORTS (TB * GSTRIDE)       // 8864 shorts = 17728 B per buffer
#define NCOLS (TB * HALO)              // 184 valid gtile columns (12 tiles, last partial)

__device__ __forceinline__ unsigned short f2bf(float f) {
    unsigned int u = __float_as_uint(f);
    u += 0x7fff + ((u >> 16) & 1);   // RNE
    return (unsigned short)(u >> 16);
}

// packed f32x2 -> bf16x2 (v_cvt_pk_bf16_f32, RNE)
__device__ __forceinline__ unsigned int pk_bf16(float lo, float hi) {
    float2 f; f.x = lo; f.y = hi;
    __hip_bfloat162 h = __float22bfloat162_rn(f);
    union { __hip_bfloat162 b; unsigned int u; } c;
    c.b = h;
    return c.u;
}

// force a uniform value into SGPR
__device__ __forceinline__ float sload(const float* p) {
    return __uint_as_float(__builtin_amdgcn_readfirstlane(__float_as_uint(*p)));
}

// R8: barrier-decoupling test. Same per-wave code/registers as R7 (ks-outer p3, T14
// staging, poly-hoist, setprio), but 128-thread blocks (2 waves), TB=4, 4 blocks/CU:
// barriers sync 2 waves not 4, and each CU hosts 4 independently-drifting blocks so
// one block's barrier drain overlaps 3 others' compute (R6 showed in-wave reordering
// is the WRONG way to decouple — this changes no instruction order within a wave).
// History: >2 waves/SIMD DEAD (regs, R1/R3); fragment arrays by-ref -> scratch (R5);
// intra-wave ILP restructures all neutral (R4/R7). VGPR_Count is NOT a spill guard;
// WRITE_SIZE is (10.24 MB clean, 20MB+ = spill).
__global__ __launch_bounds__(NTHREADS, 2) void lorenz96_fused(
    const float* __restrict__ u,
    const float* __restrict__ coeff,
    const float* __restrict__ W1,
    const float* __restrict__ b1,
    const float* __restrict__ W2,
    const float* __restrict__ b2,
    const float* __restrict__ W3,
    const float* __restrict__ b3,
    float* __restrict__ out)
{
    // LDS: gtile 2x17728 (staging alias spans BOTH buffers; consumed before any phase2
    // write) + u_sbuf 1600 = 37056 B -> 4 blocks/CU (148.2 KB)
    __shared__ __align__(16) unsigned short gtile[2][GT_SHORTS];
    __shared__ __align__(16) float u_sbuf[2][TB * USTRIDE];   // u_s[b][k] = u[b][(k+36)%40]

    unsigned short* B_lds = &gtile[0][0];   // alias: 12288 shorts, spans gtile[0]+gtile[1]

    const int t    = threadIdx.x;
    const int lane = t & 63;
    const int wave = t >> 6;                 // 0..1
    const int quad = lane >> 4;
    const int l15  = lane & 15;

    const int b0_block = blockIdx.x * (TB * NBG);

    // ---------- init 0a: W2 staging, pre-swizzled; k=240 carries b2 (bias row, B supplies 1.0) ----------
    // W2eff[o][k = tap*48 + c] = W2[o][c][tap]; lane holds [o = nt*16+l15][k = ks*32+quad*8+j]
    for (int g = t; g < NT * 8 * 64; g += NTHREADS) {
        int lg = g & 63;
        int ks = (g >> 6) & 7;
        int nt = g >> 9;
        int o  = nt * 16 + (lg & 15);
        int kb = ks * 32 + (lg >> 4) * 8;
        s16x8 pack = {0, 0, 0, 0, 0, 0, 0, 0};
        #pragma unroll
        for (int j = 0; j < 8; ++j) {
            int k = kb + j;
            if (o < 37) {
                if (k < 240) {
                    int c = k % 48, tap = k / 48;
                    pack[j] = (short)f2bf(W2[o * 240 + c * 5 + tap]);
                } else if (k == 240) {
                    pack[j] = (short)f2bf(b2[o]);
                }
            }
        }
        *(s16x8*)&B_lds[g * 8] = pack;
    }

    // ---------- init 0b: conv1 A-fragments (W1 + fused b1 at k=5) ----------
    // tiles: T0=ch0-15, T1=ch16-31, T2=ch32-47, T3 rows8-15=ch48-55, T4=ch56-71.
    // GLU in-lane: T1 rows8-15 x T3 rows8-15; T2 x T4 (same quad,reg).
    s16x8 aW1[5];
    {
        int chs[5];
        chs[0] = l15; chs[1] = 16 + l15; chs[2] = 32 + l15;
        chs[3] = (l15 >= 8) ? 40 + l15 : -1;
        chs[4] = 56 + l15;
        #pragma unroll
        for (int mt = 0; mt < 5; ++mt) {
            s16x8 a = {0, 0, 0, 0, 0, 0, 0, 0};
            int ch = chs[mt];
            if (quad == 0 && ch >= 0) {
                #pragma unroll
                for (int j = 0; j < 5; ++j) a[j] = (short)f2bf(W1[ch * 5 + j]);
                a[5] = (short)f2bf(b1[ch]);   // bias slot; B supplies 1.0 at k=5
            }
            aW1[mt] = a;
        }
    }

    // ---------- init 0c: epilogue constants (b2 folded into GEMM; only W3 left) ----------
    float w3v[NT][4];
    #pragma unroll
    for (int nt = 0; nt < NT; ++nt)
        #pragma unroll
        for (int r = 0; r < 4; ++r) {
            int o = nt * 16 + quad * 4 + r;
            w3v[nt][r] = (o < 37) ? W3[o] : 0.f;
        }
    const float b3v = sload(b3);
    float cf[18];
    #pragma unroll
    for (int i = 0; i < 18; ++i) cf[i] = sload(&coeff[i]);   // SGPR-resident

    // stage-2 A-fragments (declared before lambdas so they capture it)
    s16x8 aW2[NT][8];
    // poly regs: pv_q = row of tile i=quad (mt=wave+2*quad); pv_4 = row of tile i=4 (mt=wave+8)
    float pv_q = 0.f, pv_4 = 0.f;
    // T14 staging registers (static-indexed -> stay in VGPRs)
    float st_v0 = 0.f, st_v1 = 0.f;

    // ---------- helpers ----------
    auto prestage_u = [&](int grp) {   // prologue-only: full stage of group grp into u_sbuf[grp&1]
        for (int idx = t; idx < TB * USTRIDE; idx += NTHREADS) {
            int b = idx / USTRIDE, k = idx - b * USTRIDE;
            int gi = k + 36; gi -= (gi >= 40) ? 40 : 0; gi -= (gi >= 40) ? 40 : 0;
            u_sbuf[grp & 1][idx] = u[(size_t)(b0_block + grp * TB + b) * 40 + gi];
        }
    };

    auto prestage_issue = [&](int grp) {   // T14 part 1: issue global loads into regs
        {
            int idx = t;                                   // t < 128 < 200 always
            int b = idx / USTRIDE, k = idx - b * USTRIDE;
            int gi = k + 36; gi -= (gi >= 40) ? 40 : 0; gi -= (gi >= 40) ? 40 : 0;
            st_v0 = u[(size_t)(b0_block + grp * TB + b) * 40 + gi];
        }
        if (t + NTHREADS < TB * USTRIDE) {                 // t < 72
            int idx = t + NTHREADS;
            int b = idx / USTRIDE, k = idx - b * USTRIDE;
            int gi = k + 36; gi -= (gi >= 40) ? 40 : 0; gi -= (gi >= 40) ? 40 : 0;
            st_v1 = u[(size_t)(b0_block + grp * TB + b) * 40 + gi];
        }
    };

    auto prestage_commit = [&](int grp) {  // T14 part 2: LDS writes (just before barrier)
        u_sbuf[grp & 1][t] = st_v0;
        if (t + NTHREADS < TB * USTRIDE) u_sbuf[grp & 1][t + NTHREADS] = st_v1;
    };

    auto poly1 = [&](const float* u_s, int m) -> float {   // poly term for output row m
        int p = m >> 2, b = m & 3;                         // TB=4 row decomposition
        const float* us = &u_s[b * USTRIDE + p];
        float um2 = us[2], um1 = us[3], u0 = us[4], up1 = us[5], up2 = us[6];
        return cf[0] + cf[1]*um2 + cf[2]*um1 + cf[3]*u0 + cf[4]*up1 + cf[5]*up2
             + cf[6]*um2*um2 + cf[7]*um1*um1 + cf[8]*u0*u0 + cf[9]*up1*up1 + cf[10]*up2*up2
             + cf[11]*um2*um1 + cf[12]*um1*u0 + cf[13]*u0*up1 + cf[14]*up1*up2
             + cf[15]*um2*u0 + cf[16]*um1*up1 + cf[17]*u0*up2;
    };

    auto phase2 = [&](int gi) {       // conv1 via MFMA + GLU -> gtile[gi&1]
        const float* u_s = u_sbuf[gi & 1];
        unsigned short* gt = &gtile[gi & 1][0];
        #pragma unroll
        for (int i = 0; i < 6; ++i) {
            const int ct = wave + 2 * i;                // col-tiles 0..11 (perfectly balanced 6/6)
            const int col = ct * 16 + l15;
            const bool valid = col < NCOLS;             // tile 11 partial: cols 184-191 dead
            const int b = col & 3, h = col >> 2;        // h <= 45 < HALO when valid
            s16x8 bU = {0, 0, 0, 0, 0, 0, 0, 0};
            if (quad == 0 && valid) {                   // exec-masked: only 16 lanes touch LDS
                const float* us = &u_s[b * USTRIDE + h];   // taps u[(h-4+j)%40], j=0..4
                union { s16x8 v; unsigned int w[4]; } bu;
                bu.w[0] = pk_bf16(us[0], us[1]);
                bu.w[1] = pk_bf16(us[2], us[3]);
                bu.w[2] = pk_bf16(us[4], 1.0f);            // 1.0 -> bias slot k=5
                bu.w[3] = 0;
                bU = bu.v;
            }
            f32x4 a0 = {0.f,0.f,0.f,0.f}, a1 = a0, a2 = a0, a3 = a0, a4 = a0;
            a0 = __builtin_amdgcn_mfma_f32_16x16x32_bf16(aW1[0], bU, a0, 0, 0, 0);
            a1 = __builtin_amdgcn_mfma_f32_16x16x32_bf16(aW1[1], bU, a1, 0, 0, 0);
            a2 = __builtin_amdgcn_mfma_f32_16x16x32_bf16(aW1[2], bU, a2, 0, 0, 0);
            a3 = __builtin_amdgcn_mfma_f32_16x16x32_bf16(aW1[3], bU, a3, 0, 0, 0);
            a4 = __builtin_amdgcn_mfma_f32_16x16x32_bf16(aW1[4], bU, a4, 0, 0, 0);
            float v0[4], v1[4], v2[4];
            #pragma unroll
            for (int r = 0; r < 4; ++r) {
                v0[r] = fmaxf(a0[r], 0.f);
                v1[r] = fmaxf(a1[r], 0.f);
                if (quad >= 2) v1[r] *= fmaxf(a3[r], 0.f);          // ch24-31 gate
                v2[r] = fmaxf(a2[r], 0.f) * fmaxf(a4[r], 0.f);      // ch32-47 gate
            }
            union { s16x4 v; unsigned int w[2]; } w0, w1, w2;
            w0.w[0] = pk_bf16(v0[0], v0[1]); w0.w[1] = pk_bf16(v0[2], v0[3]);
            w1.w[0] = pk_bf16(v1[0], v1[1]); w1.w[1] = pk_bf16(v1[2], v1[3]);
            w2.w[0] = pk_bf16(v2[0], v2[1]); w2.w[1] = pk_bf16(v2[2], v2[3]);
            if (valid) {
                unsigned short* gp = &gt[b * GSTRIDE + h * 48 + quad * 4];
                *(s16x4*)(gp)      = w0.v;
                *(s16x4*)(gp + 16) = w1.v;
                *(s16x4*)(gp + 32) = w2.v;
            }
        }
    };

// ---- p3 macros: ks-outer over tile batches (R7 structure); TB=4 row decomposition ----
#define P3_EPI(In, A0, A1, A2)                                                      \
    do {                                                                            \
        float s_ = 0.f;                                                             \
        _Pragma("unroll")                                                           \
        for (int r = 0; r < 4; ++r) {                                               \
            s_ += fmaxf((A0)[r], 0.f) * w3v[0][r];                                  \
            s_ += fmaxf((A1)[r], 0.f) * w3v[1][r];                                  \
            s_ += fmaxf((A2)[r], 0.f) * w3v[2][r];                                  \
        }                                                                           \
        s_ += __shfl_xor(s_, 16, 64);                                               \
        s_ += __shfl_xor(s_, 32, 64);                                               \
        const float pv_ = ((In) < 4) ? pv_q : pv_4;                                 \
        const bool  st_ = ((In) < 4) ? (quad == (In)) : (quad == 0);                \
        if (st_)   /* row m = (wave+2*In)*16+l15 -> out[b0 + (m&3)][m>>2] */        \
            out[(size_t)(b0 + (l15 & 3)) * 40 + (wave + 2 * (In)) * 4 + (l15 >> 2)] \
                = s_ + b3v + pv_;                                                   \
    } while (0)

#define P3_TRIO(I0, I1, I2)                                                         \
    do {                                                                            \
        const int m0_ = (wave + 2 * (I0)) * 16 + l15;                               \
        const int m1_ = (wave + 2 * (I1)) * 16 + l15;                               \
        const int m2_ = (wave + 2 * (I2)) * 16 + l15;                               \
        const unsigned short* gb0_ = &gt[(m0_ & 3) * GSTRIDE + (m0_ >> 2) * 48 + quad * 8]; \
        const unsigned short* gb1_ = &gt[(m1_ & 3) * GSTRIDE + (m1_ >> 2) * 48 + quad * 8]; \
        const unsigned short* gb2_ = &gt[(m2_ & 3) * GSTRIDE + (m2_ >> 2) * 48 + quad * 8]; \
        f32x4 a00_ = {0.f,0.f,0.f,0.f}, a01_ = a00_, a02_ = a00_;                   \
        f32x4 a10_ = a00_, a11_ = a00_, a12_ = a00_;                                \
        f32x4 a20_ = a00_, a21_ = a00_, a22_ = a00_;                                \
        __builtin_amdgcn_s_setprio(1);                                              \
        _Pragma("unroll")                                                           \
        for (int ks = 0; ks < 8; ++ks) {                                            \
            s16x8 bq0_ = *(const s16x8*)(gb0_ + ks * 32);                           \
            s16x8 bq1_ = *(const s16x8*)(gb1_ + ks * 32);                           \
            s16x8 bq2_ = *(const s16x8*)(gb2_ + ks * 32);                           \
            if (ks == 7 && quad == 2) {   /* bias row k=240 reads 1.0 */            \
                bq0_[0] = (short)0x3F80; bq1_[0] = (short)0x3F80; bq2_[0] = (short)0x3F80; \
            }                                                                       \
            a00_ = __builtin_amdgcn_mfma_f32_16x16x32_bf16(aW2[0][ks], bq0_, a00_, 0, 0, 0); \
            a10_ = __builtin_amdgcn_mfma_f32_16x16x32_bf16(aW2[0][ks], bq1_, a10_, 0, 0, 0); \
            a20_ = __builtin_amdgcn_mfma_f32_16x16x32_bf16(aW2[0][ks], bq2_, a20_, 0, 0, 0); \
            a01_ = __builtin_amdgcn_mfma_f32_16x16x32_bf16(aW2[1][ks], bq0_, a01_, 0, 0, 0); \
            a11_ = __builtin_amdgcn_mfma_f32_16x16x32_bf16(aW2[1][ks], bq1_, a11_, 0, 0, 0); \
            a21_ = __builtin_amdgcn_mfma_f32_16x16x32_bf16(aW2[1][ks], bq2_, a21_, 0, 0, 0); \
            a02_ = __builtin_amdgcn_mfma_f32_16x16x32_bf16(aW2[2][ks], bq0_, a02_, 0, 0, 0); \
            a12_ = __builtin_amdgcn_mfma_f32_16x16x32_bf16(aW2[2][ks], bq1_, a12_, 0, 0, 0); \
            a22_ = __builtin_amdgcn_mfma_f32_16x16x32_bf16(aW2[2][ks], bq2_, a22_, 0, 0, 0); \
        }                                                                           \
        __builtin_amdgcn_s_setprio(0);                                              \
        P3_EPI(I0, a00_, a01_, a02_);                                               \
        P3_EPI(I1, a10_, a11_, a12_);                                               \
        P3_EPI(I2, a20_, a21_, a22_);                                               \
    } while (0)

#define P3_DUO(I0, I1)                                                              \
    do {                                                                            \
        const int m0_ = (wave + 2 * (I0)) * 16 + l15;                               \
        const int m1_ = (wave + 2 * (I1)) * 16 + l15;                               \
        const unsigned short* gb0_ = &gt[(m0_ & 3) * GSTRIDE + (m0_ >> 2) * 48 + quad * 8]; \
        const unsigned short* gb1_ = &gt[(m1_ & 3) * GSTRIDE + (m1_ >> 2) * 48 + quad * 8]; \
        f32x4 a00_ = {0.f,0.f,0.f,0.f}, a01_ = a00_, a02_ = a00_;                   \
        f32x4 a10_ = a00_, a11_ = a00_, a12_ = a00_;                                \
        __builtin_amdgcn_s_setprio(1);                                              \
        _Pragma("unroll")                                                           \
        for (int ks = 0; ks < 8; ++ks) {                                            \
            s16x8 bq0_ = *(const s16x8*)(gb0_ + ks * 32);                           \
            s16x8 bq1_ = *(const s16x8*)(gb1_ + ks * 32);                           \
            if (ks == 7 && quad == 2) {                                             \
                bq0_[0] = (short)0x3F80; bq1_[0] = (short)0x3F80;                   \
            }                                                                       \
            a00_ = __builtin_amdgcn_mfma_f32_16x16x32_bf16(aW2[0][ks], bq0_, a00_, 0, 0, 0); \
            a10_ = __builtin_amdgcn_mfma_f32_16x16x32_bf16(aW2[0][ks], bq1_, a10_, 0, 0, 0); \
            a01_ = __builtin_amdgcn_mfma_f32_16x16x32_bf16(aW2[1][ks], bq0_, a01_, 0, 0, 0); \
            a11_ = __builtin_amdgcn_mfma_f32_16x16x32_bf16(aW2[1][ks], bq1_, a11_, 0, 0, 0); \
            a02_ = __builtin_amdgcn_mfma_f32_16x16x32_bf16(aW2[2][ks], bq0_, a02_, 0, 0, 0); \
            a12_ = __builtin_amdgcn_mfma_f32_16x16x32_bf16(aW2[2][ks], bq1_, a12_, 0, 0, 0); \
        }                                                                           \
        __builtin_amdgcn_s_setprio(0);                                              \
        P3_EPI(I0, a00_, a01_, a02_);                                               \
        P3_EPI(I1, a10_, a11_, a12_);                                               \
    } while (0)

    // ---------- prologue ----------
    prestage_u(0);
    __syncthreads();   // B1: B_lds (both-buffer alias) + u_sbuf[0] ready

    #pragma unroll
    for (int nt = 0; nt < NT; ++nt)
        #pragma unroll
        for (int ks = 0; ks < 8; ++ks)
            aW2[nt][ks] = *(const s16x8*)&B_lds[((nt * 8 + ks) * 64 + lane) * 8];

    {   // poly for group 0
        const float* u_s = u_sbuf[0];
        pv_q = poly1(u_s, (wave + 2 * quad) * 16 + l15);
        pv_4 = poly1(u_s, (wave + 8) * 16 + l15);
    }
    prestage_u(1);
    __syncthreads();   // B2: aW2 fragment reads done -> safe to overwrite gtile[0]/[1]

    phase2(0);
    __syncthreads();   // B3: gtile[0] ready

    // ---------- main loop ----------
    // interval g: [issue u-loads g+2] [poly(g+1)->temps] P3(g) phase2(g+1) [commit u g+2] barrier
    // (R6 lesson: keep {P3; phase2} order — compiler fills P3's stalls with phase2 work)
    for (int g = 0; g < NBG; ++g) {
        const int b0 = b0_block + g * TB;
        const unsigned short* gt = &gtile[g & 1][0];

        if (g + 2 < NBG) prestage_issue(g + 2);          // loads in flight across the interval

        float tq = 0.f, t4 = 0.f;
        if (g + 1 < NBG) {                                // poly for g+1: independent VALU work
            const float* u_s = u_sbuf[(g + 1) & 1];       // ready since previous interval
            tq = poly1(u_s, (wave + 2 * quad) * 16 + l15);
            t4 = poly1(u_s, (wave + 8) * 16 + l15);
        }

        P3_TRIO(0, 1, 2);                                 // consumes pv (group g)
        P3_DUO(3, 4);

        if (g + 1 < NBG) {
            phase2(g + 1);                                // writes gtile[(g+1)&1] (opposite buffer)
            if (g + 2 < NBG) prestage_commit(g + 2);      // vmcnt + LDS write, latency already hidden
            pv_q = tq; pv_4 = t4;                         // pv regs now hold group g+1
            __syncthreads();                              // window barrier: gtile[(g+1)&1] ready
        }
    }
}

extern "C" void kernel_launch(void* const* d_in, const int* in_sizes, int n_in,
                              void* d_out, int out_size, void* d_ws, size_t ws_size,
                              hipStream_t stream) {
    // inputs: 0=t(unused), 1=u, 2=coeff, 3=W1, 4=b1, 5=W2, 6=b2, 7=W3, 8=b3
    const float* u     = (const float*)d_in[1];
    const float* coeff = (const float*)d_in[2];
    const float* W1    = (const float*)d_in[3];
    const float* b1    = (const float*)d_in[4];
    const float* W2    = (const float*)d_in[5];
    const float* b2    = (const float*)d_in[6];
    const float* W3    = (const float*)d_in[7];
    const float* b3    = (const float*)d_in[8];
    float* out = (float*)d_out;

    const int n_batch = in_sizes[1] / 40;            // 65536
    const int grid = n_batch / (TB * NBG);           // 1024 blocks = 4 blocks/CU exactly
    lorenz96_fused<<<grid, NTHREADS, 0, stream>>>(u, coeff, W1, b1, W2, b2, W3, b3, out);
}

// Round 9
// 176.972 us; speedup vs baseline: 1.0518x; 1.0518x over previous
//
#include <hip/hip_runtime.h>
#include <hip/hip_bf16.h>

typedef short s16x8 __attribute__((ext_vector_type(8)));
typedef short s16x4 __attribute__((ext_vector_type(4)));
typedef float f32x4 __attribute__((ext_vector_type(4)));

#define TB 8            // batch elements per group
#define NBG 16          // groups per block; grid 512 = exactly 2 blocks/CU
#define HALO 46         // gtile positions per batch (pos -2 .. 43)
#define GSTRIDE 2216    // shorts per batch in gtile (8*odd: bank-decorrelated)
#define USTRIDE 50      // floats per batch in u_s halo
#define NT 3            // stage-2 N tiles (48 cols, >=37 zero-padded; k=240 = b2 row)
#define GT_SHORTS (TB * GSTRIDE)       // 17728 shorts = 35456 B per buffer

__device__ __forceinline__ unsigned short f2bf(float f) {
    unsigned int u = __float_as_uint(f);
    u += 0x7fff + ((u >> 16) & 1);   // RNE
    return (unsigned short)(u >> 16);
}

// packed f32x2 -> bf16x2 (v_cvt_pk_bf16_f32, RNE)
__device__ __forceinline__ unsigned int pk_bf16(float lo, float hi) {
    float2 f; f.x = lo; f.y = hi;
    __hip_bfloat162 h = __float22bfloat162_rn(f);
    union { __hip_bfloat162 b; unsigned int u; } c;
    c.b = h;
    return c.u;
}

// force a uniform value into SGPR
__device__ __forceinline__ float sload(const float* p) {
    return __uint_as_float(__builtin_amdgcn_readfirstlane(__float_as_uint(*p)));
}

// CHAMPION (R7, rocprof 114.9us): (256,2), T14 staging split + poly hoist (R2, +4%),
// ks-outer p3 trios (R7, neutral but kept: -stalls exposed 2x not 5x), setprio(1) on MFMA.
// Closed paths (measured): >2 waves/SIMD (R1/R3: spill/1-block — weights=116 AGPR/wave);
// fragment arrays by-ref across lambdas (R5: scratch, WRITE_SIZE 100MB); phase reorder
// (R6: -12%, kills compiler cross-phase fusion); smaller blocks for barrier decoupling
// (R8: -8%, staging overhead doubles, coupling wasn't the stall); intra-wave MFMA-chain
// ILP (R4/R7: null — TLP+compiler already cover it). fp8 stage-2 closed by accuracy
// (absmax at 0.0625 threshold). Floor is distributed dependency latency at the
// register-forced 2 waves/SIMD; all pipes <50%.
// Guards: WRITE_SIZE == 10.24 MB, LDS 74240, VGPR ~128.
__global__ __launch_bounds__(256, 2) void lorenz96_fused(
    const float* __restrict__ u,
    const float* __restrict__ coeff,
    const float* __restrict__ W1,
    const float* __restrict__ b1,
    const float* __restrict__ W2,
    const float* __restrict__ b2,
    const float* __restrict__ W3,
    const float* __restrict__ b3,
    float* __restrict__ out)
{
    // LDS: gtile 2x35456 (buf0 aliases W2 staging) + u_sbuf 3200 = 74112 B -> 2 blocks/CU
    __shared__ __align__(16) unsigned short gtile[2][GT_SHORTS];
    __shared__ __align__(16) float u_sbuf[2][TB * USTRIDE];   // u_s[b][k] = u[b][(k+36)%40]

    unsigned short* B_lds = &gtile[0][0];   // alias: consumed into regs before gtile[0] is written

    const int t    = threadIdx.x;
    const int lane = t & 63;
    const int wave = t >> 6;
    const int quad = lane >> 4;
    const int l15  = lane & 15;

    const int b0_block = blockIdx.x * (TB * NBG);

    // ---------- init 0a: W2 staging, pre-swizzled; k=240 carries b2 (bias row, B supplies 1.0) ----------
    // W2eff[o][k = tap*48 + c] = W2[o][c][tap]; lane holds [o = nt*16+l15][k = ks*32+quad*8+j]
    for (int g = t; g < NT * 8 * 64; g += 256) {
        int lg = g & 63;
        int ks = (g >> 6) & 7;
        int nt = g >> 9;
        int o  = nt * 16 + (lg & 15);
        int kb = ks * 32 + (lg >> 4) * 8;
        s16x8 pack = {0, 0, 0, 0, 0, 0, 0, 0};
        #pragma unroll
        for (int j = 0; j < 8; ++j) {
            int k = kb + j;
            if (o < 37) {
                if (k < 240) {
                    int c = k % 48, tap = k / 48;
                    pack[j] = (short)f2bf(W2[o * 240 + c * 5 + tap]);
                } else if (k == 240) {
                    pack[j] = (short)f2bf(b2[o]);
                }
            }
        }
        *(s16x8*)&B_lds[g * 8] = pack;
    }

    // ---------- init 0b: conv1 A-fragments (W1 + fused b1 at k=5) ----------
    // tiles: T0=ch0-15, T1=ch16-31, T2=ch32-47, T3 rows8-15=ch48-55, T4=ch56-71.
    // GLU in-lane: T1 rows8-15 x T3 rows8-15; T2 x T4 (same quad,reg).
    s16x8 aW1[5];
    {
        int chs[5];
        chs[0] = l15; chs[1] = 16 + l15; chs[2] = 32 + l15;
        chs[3] = (l15 >= 8) ? 40 + l15 : -1;
        chs[4] = 56 + l15;
        #pragma unroll
        for (int mt = 0; mt < 5; ++mt) {
            s16x8 a = {0, 0, 0, 0, 0, 0, 0, 0};
            int ch = chs[mt];
            if (quad == 0 && ch >= 0) {
                #pragma unroll
                for (int j = 0; j < 5; ++j) a[j] = (short)f2bf(W1[ch * 5 + j]);
                a[5] = (short)f2bf(b1[ch]);   // bias slot; B supplies 1.0 at k=5
            }
            aW1[mt] = a;
        }
    }

    // ---------- init 0c: epilogue constants (b2 folded into GEMM; only W3 left) ----------
    float w3v[NT][4];
    #pragma unroll
    for (int nt = 0; nt < NT; ++nt)
        #pragma unroll
        for (int r = 0; r < 4; ++r) {
            int o = nt * 16 + quad * 4 + r;
            w3v[nt][r] = (o < 37) ? W3[o] : 0.f;
        }
    const float b3v = sload(b3);
    float cf[18];
    #pragma unroll
    for (int i = 0; i < 18; ++i) cf[i] = sload(&coeff[i]);   // SGPR-resident

    // stage-2 A-fragments (declared before lambdas so they capture it)
    s16x8 aW2[NT][8];
    // poly term registers: pv_q = row of tile i=quad; pv_4 = row of tile i=4 (valid on quad 0)
    float pv_q = 0.f, pv_4 = 0.f;
    // T14 staging registers for the split prestage (static-indexed -> stay in VGPRs)
    float st_v0 = 0.f, st_v1 = 0.f;

    // ---------- helpers ----------
    auto prestage_u = [&](int grp) {   // prologue-only: full stage of group grp into u_sbuf[grp&1]
        for (int idx = t; idx < TB * USTRIDE; idx += 256) {
            int b = idx / USTRIDE, k = idx - b * USTRIDE;
            int gi = k + 36; gi -= (gi >= 40) ? 40 : 0; gi -= (gi >= 40) ? 40 : 0;
            u_sbuf[grp & 1][idx] = u[(size_t)(b0_block + grp * TB + b) * 40 + gi];
        }
    };

    auto prestage_issue = [&](int grp) {   // T14 part 1: issue global loads into regs
        {
            int idx = t;                                   // idx < 400 always (t < 256)
            int b = idx / USTRIDE, k = idx - b * USTRIDE;
            int gi = k + 36; gi -= (gi >= 40) ? 40 : 0; gi -= (gi >= 40) ? 40 : 0;
            st_v0 = u[(size_t)(b0_block + grp * TB + b) * 40 + gi];
        }
        if (t + 256 < TB * USTRIDE) {
            int idx = t + 256;
            int b = idx / USTRIDE, k = idx - b * USTRIDE;
            int gi = k + 36; gi -= (gi >= 40) ? 40 : 0; gi -= (gi >= 40) ? 40 : 0;
            st_v1 = u[(size_t)(b0_block + grp * TB + b) * 40 + gi];
        }
    };

    auto prestage_commit = [&](int grp) {  // T14 part 2: LDS writes (just before barrier)
        u_sbuf[grp & 1][t] = st_v0;
        if (t + 256 < TB * USTRIDE) u_sbuf[grp & 1][t + 256] = st_v1;
    };

    auto poly1 = [&](const float* u_s, int m) -> float {   // poly term for output row m
        int p = m >> 3, b = m & 7;
        const float* us = &u_s[b * USTRIDE + p];
        float um2 = us[2], um1 = us[3], u0 = us[4], up1 = us[5], up2 = us[6];
        return cf[0] + cf[1]*um2 + cf[2]*um1 + cf[3]*u0 + cf[4]*up1 + cf[5]*up2
             + cf[6]*um2*um2 + cf[7]*um1*um1 + cf[8]*u0*u0 + cf[9]*up1*up1 + cf[10]*up2*up2
             + cf[11]*um2*um1 + cf[12]*um1*u0 + cf[13]*u0*up1 + cf[14]*up1*up2
             + cf[15]*um2*u0 + cf[16]*um1*up1 + cf[17]*u0*up2;
    };

    auto phase2 = [&](int gi) {       // conv1 via MFMA + GLU -> gtile[gi&1]
        const float* u_s = u_sbuf[gi & 1];
        unsigned short* gt = &gtile[gi & 1][0];
        #pragma unroll
        for (int i = 0; i < 6; ++i) {
            const int ct = wave + 4 * i;               // col-tiles 0..22 live (cols 0..367)
            if (ct > 22) continue;                      // only wave3,i=5: cols 368+ are pad
            const int col = ct * 16 + l15;
            const int b = col & 7, h = col >> 3;        // h <= 45 < HALO always
            s16x8 bU = {0, 0, 0, 0, 0, 0, 0, 0};
            if (quad == 0) {                            // exec-masked: only 16 lanes touch LDS
                const float* us = &u_s[b * USTRIDE + h];   // taps u[(h-4+j)%40], j=0..4
                union { s16x8 v; unsigned int w[4]; } bu;
                bu.w[0] = pk_bf16(us[0], us[1]);
                bu.w[1] = pk_bf16(us[2], us[3]);
                bu.w[2] = pk_bf16(us[4], 1.0f);            // 1.0 -> bias slot k=5
                bu.w[3] = 0;
                bU = bu.v;
            }
            f32x4 a0 = {0.f,0.f,0.f,0.f}, a1 = a0, a2 = a0, a3 = a0, a4 = a0;
            a0 = __builtin_amdgcn_mfma_f32_16x16x32_bf16(aW1[0], bU, a0, 0, 0, 0);
            a1 = __builtin_amdgcn_mfma_f32_16x16x32_bf16(aW1[1], bU, a1, 0, 0, 0);
            a2 = __builtin_amdgcn_mfma_f32_16x16x32_bf16(aW1[2], bU, a2, 0, 0, 0);
            a3 = __builtin_amdgcn_mfma_f32_16x16x32_bf16(aW1[3], bU, a3, 0, 0, 0);
            a4 = __builtin_amdgcn_mfma_f32_16x16x32_bf16(aW1[4], bU, a4, 0, 0, 0);
            float v0[4], v1[4], v2[4];
            #pragma unroll
            for (int r = 0; r < 4; ++r) {
                v0[r] = fmaxf(a0[r], 0.f);
                v1[r] = fmaxf(a1[r], 0.f);
                if (quad >= 2) v1[r] *= fmaxf(a3[r], 0.f);          // ch24-31 gate
                v2[r] = fmaxf(a2[r], 0.f) * fmaxf(a4[r], 0.f);      // ch32-47 gate
            }
            union { s16x4 v; unsigned int w[2]; } w0, w1, w2;
            w0.w[0] = pk_bf16(v0[0], v0[1]); w0.w[1] = pk_bf16(v0[2], v0[3]);
            w1.w[0] = pk_bf16(v1[0], v1[1]); w1.w[1] = pk_bf16(v1[2], v1[3]);
            w2.w[0] = pk_bf16(v2[0], v2[1]); w2.w[1] = pk_bf16(v2[2], v2[3]);
            unsigned short* gp = &gt[b * GSTRIDE + h * 48 + quad * 4];
            *(s16x4*)(gp)      = w0.v;
            *(s16x4*)(gp + 16) = w1.v;
            *(s16x4*)(gp + 32) = w2.v;
        }
    };

// ---- p3 macros: ks-outer over tile batches; all names local to each do-block ----
// epilogue for one tile In with accumulators A0/A1/A2 (nt = 0/1/2)
#define P3_EPI(In, A0, A1, A2)                                                      \
    do {                                                                            \
        float s_ = 0.f;                                                             \
        _Pragma("unroll")                                                           \
        for (int r = 0; r < 4; ++r) {                                               \
            s_ += fmaxf((A0)[r], 0.f) * w3v[0][r];                                  \
            s_ += fmaxf((A1)[r], 0.f) * w3v[1][r];                                  \
            s_ += fmaxf((A2)[r], 0.f) * w3v[2][r];                                  \
        }                                                                           \
        s_ += __shfl_xor(s_, 16, 64);                                               \
        s_ += __shfl_xor(s_, 32, 64);                                               \
        const float pv_ = ((In) < 4) ? pv_q : pv_4;                                 \
        const bool  st_ = ((In) < 4) ? (quad == (In)) : (quad == 0);                \
        if (st_)                                                                    \
            out[(size_t)(b0 + (l15 & 7)) * 40 + 2 * (wave + 4 * (In)) + (l15 >> 3)] \
                = s_ + b3v + pv_;                                                   \
    } while (0)

// three tiles, ks-outer: per ks {3 ds_read_b128 + 9 independent MFMA}
#define P3_TRIO(I0, I1, I2)                                                         \
    do {                                                                            \
        const int m0_ = (wave + 4 * (I0)) * 16 + l15;                               \
        const int m1_ = (wave + 4 * (I1)) * 16 + l15;                               \
        const int m2_ = (wave + 4 * (I2)) * 16 + l15;                               \
        const unsigned short* gb0_ = &gt[(m0_ & 7) * GSTRIDE + (m0_ >> 3) * 48 + quad * 8]; \
        const unsigned short* gb1_ = &gt[(m1_ & 7) * GSTRIDE + (m1_ >> 3) * 48 + quad * 8]; \
        const unsigned short* gb2_ = &gt[(m2_ & 7) * GSTRIDE + (m2_ >> 3) * 48 + quad * 8]; \
        f32x4 a00_ = {0.f,0.f,0.f,0.f}, a01_ = a00_, a02_ = a00_;                   \
        f32x4 a10_ = a00_, a11_ = a00_, a12_ = a00_;                                \
        f32x4 a20_ = a00_, a21_ = a00_, a22_ = a00_;                                \
        __builtin_amdgcn_s_setprio(1);                                              \
        _Pragma("unroll")                                                           \
        for (int ks = 0; ks < 8; ++ks) {                                            \
            s16x8 bq0_ = *(const s16x8*)(gb0_ + ks * 32);                           \
            s16x8 bq1_ = *(const s16x8*)(gb1_ + ks * 32);                           \
            s16x8 bq2_ = *(const s16x8*)(gb2_ + ks * 32);                           \
            if (ks == 7 && quad == 2) {   /* bias row k=240 reads 1.0 */            \
                bq0_[0] = (short)0x3F80; bq1_[0] = (short)0x3F80; bq2_[0] = (short)0x3F80; \
            }                                                                       \
            a00_ = __builtin_amdgcn_mfma_f32_16x16x32_bf16(aW2[0][ks], bq0_, a00_, 0, 0, 0); \
            a10_ = __builtin_amdgcn_mfma_f32_16x16x32_bf16(aW2[0][ks], bq1_, a10_, 0, 0, 0); \
            a20_ = __builtin_amdgcn_mfma_f32_16x16x32_bf16(aW2[0][ks], bq2_, a20_, 0, 0, 0); \
            a01_ = __builtin_amdgcn_mfma_f32_16x16x32_bf16(aW2[1][ks], bq0_, a01_, 0, 0, 0); \
            a11_ = __builtin_amdgcn_mfma_f32_16x16x32_bf16(aW2[1][ks], bq1_, a11_, 0, 0, 0); \
            a21_ = __builtin_amdgcn_mfma_f32_16x16x32_bf16(aW2[1][ks], bq2_, a21_, 0, 0, 0); \
            a02_ = __builtin_amdgcn_mfma_f32_16x16x32_bf16(aW2[2][ks], bq0_, a02_, 0, 0, 0); \
            a12_ = __builtin_amdgcn_mfma_f32_16x16x32_bf16(aW2[2][ks], bq1_, a12_, 0, 0, 0); \
            a22_ = __builtin_amdgcn_mfma_f32_16x16x32_bf16(aW2[2][ks], bq2_, a22_, 0, 0, 0); \
        }                                                                           \
        __builtin_amdgcn_s_setprio(0);                                              \
        P3_EPI(I0, a00_, a01_, a02_);                                               \
        P3_EPI(I1, a10_, a11_, a12_);                                               \
        P3_EPI(I2, a20_, a21_, a22_);                                               \
    } while (0)

// two tiles, ks-outer: per ks {2 ds_read_b128 + 6 independent MFMA}
#define P3_DUO(I0, I1)                                                              \
    do {                                                                            \
        const int m0_ = (wave + 4 * (I0)) * 16 + l15;                               \
        const int m1_ = (wave + 4 * (I1)) * 16 + l15;                               \
        const unsigned short* gb0_ = &gt[(m0_ & 7) * GSTRIDE + (m0_ >> 3) * 48 + quad * 8]; \
        const unsigned short* gb1_ = &gt[(m1_ & 7) * GSTRIDE + (m1_ >> 3) * 48 + quad * 8]; \
        f32x4 a00_ = {0.f,0.f,0.f,0.f}, a01_ = a00_, a02_ = a00_;                   \
        f32x4 a10_ = a00_, a11_ = a00_, a12_ = a00_;                                \
        __builtin_amdgcn_s_setprio(1);                                              \
        _Pragma("unroll")                                                           \
        for (int ks = 0; ks < 8; ++ks) {                                            \
            s16x8 bq0_ = *(const s16x8*)(gb0_ + ks * 32);                           \
            s16x8 bq1_ = *(const s16x8*)(gb1_ + ks * 32);                           \
            if (ks == 7 && quad == 2) {                                             \
                bq0_[0] = (short)0x3F80; bq1_[0] = (short)0x3F80;                   \
            }                                                                       \
            a00_ = __builtin_amdgcn_mfma_f32_16x16x32_bf16(aW2[0][ks], bq0_, a00_, 0, 0, 0); \
            a10_ = __builtin_amdgcn_mfma_f32_16x16x32_bf16(aW2[0][ks], bq1_, a10_, 0, 0, 0); \
            a01_ = __builtin_amdgcn_mfma_f32_16x16x32_bf16(aW2[1][ks], bq0_, a01_, 0, 0, 0); \
            a11_ = __builtin_amdgcn_mfma_f32_16x16x32_bf16(aW2[1][ks], bq1_, a11_, 0, 0, 0); \
            a02_ = __builtin_amdgcn_mfma_f32_16x16x32_bf16(aW2[2][ks], bq0_, a02_, 0, 0, 0); \
            a12_ = __builtin_amdgcn_mfma_f32_16x16x32_bf16(aW2[2][ks], bq1_, a12_, 0, 0, 0); \
        }                                                                           \
        __builtin_amdgcn_s_setprio(0);                                              \
        P3_EPI(I0, a00_, a01_, a02_);                                               \
        P3_EPI(I1, a10_, a11_, a12_);                                               \
    } while (0)

    // ---------- prologue ----------
    prestage_u(0);
    __syncthreads();   // B1: B_lds + u_sbuf[0] ready

    #pragma unroll
    for (int nt = 0; nt < NT; ++nt)
        #pragma unroll
        for (int ks = 0; ks < 8; ++ks)
            aW2[nt][ks] = *(const s16x8*)&B_lds[((nt * 8 + ks) * 64 + lane) * 8];

    {   // poly for group 0
        const float* u_s = u_sbuf[0];
        pv_q = poly1(u_s, (wave + 4 * quad) * 16 + l15);
        pv_4 = poly1(u_s, (wave + 16) * 16 + l15);
    }
    prestage_u(1);
    __syncthreads();   // B2: aW2 fragment reads done -> safe to overwrite gtile[0]

    phase2(0);
    __syncthreads();   // B3: gtile[0] ready

    // ---------- main loop ----------
    // interval g: [issue u-loads g+2] [poly(g+1)->temps] P3(g) phase2(g+1) [commit u g+2] barrier
    // (R6 lesson: keep {P3; phase2} order — the compiler fills P3's stalls with phase2 work)
    for (int g = 0; g < NBG; ++g) {
        const int b0 = b0_block + g * TB;
        const unsigned short* gt = &gtile[g & 1][0];

        if (g + 2 < NBG) prestage_issue(g + 2);          // loads in flight across the interval

        float tq = 0.f, t4 = 0.f;
        if (g + 1 < NBG) {                                // poly for g+1: independent VALU work
            const float* u_s = u_sbuf[(g + 1) & 1];       // ready since previous interval
            tq = poly1(u_s, (wave + 4 * quad) * 16 + l15);
            t4 = poly1(u_s, (wave + 16) * 16 + l15);
        }

        P3_TRIO(0, 1, 2);                                 // consumes pv (group g)
        P3_DUO(3, 4);

        if (g + 1 < NBG) {
            phase2(g + 1);                                // writes gtile[(g+1)&1] (opposite buffer)
            if (g + 2 < NBG) prestage_commit(g + 2);      // vmcnt + LDS write, latency already hidden
            pv_q = tq; pv_4 = t4;                         // pv regs now hold group g+1
            __syncthreads();                              // window barrier: gtile[(g+1)&1] ready
        }
    }
}

extern "C" void kernel_launch(void* const* d_in, const int* in_sizes, int n_in,
                              void* d_out, int out_size, void* d_ws, size_t ws_size,
                              hipStream_t stream) {
    // inputs: 0=t(unused), 1=u, 2=coeff, 3=W1, 4=b1, 5=W2, 6=b2, 7=W3, 8=b3
    const float* u     = (const float*)d_in[1];
    const float* coeff = (const float*)d_in[2];
    const float* W1    = (const float*)d_in[3];
    const float* b1    = (const float*)d_in[4];
    const float* W2    = (const float*)d_in[5];
    const float* b2    = (const float*)d_in[6];
    const float* W3    = (const float*)d_in[7];
    const float* b3    = (const float*)d_in[8];
    float* out = (float*)d_out;

    const int n_batch = in_sizes[1] / 40;            // 65536
    const int grid = n_batch / (TB * NBG);           // 512 blocks = one full 2-blocks/CU round
    lorenz96_fused<<<grid, 256, 0, stream>>>(u, coeff, W1, b1, W2, b2, W3, b3, out);
}